// Round 1
// 608.979 us; speedup vs baseline: 1.0857x; 1.0857x over previous
//
#include <hip/hip_runtime.h>
#include <cstddef>

#define BB 16
#define CC_ 64
#define HH 192
#define WW 192
#define HW2 4096
// padded channels-last x: [b][194][196][64], real data at rows 1..192, cols 1..192
#define XPH 194
#define XPW 196

typedef _Float16 f16x8 __attribute__((ext_vector_type(8)));
typedef float f32x4 __attribute__((ext_vector_type(4)));

// ---------------- Kernel W: pack wqk fp32 -> fp16 A-fragment layout --------
// wh[kc=(r*2+cihalf)][co 128][s*32 + ci%32]
__global__ __launch_bounds__(1024) void k_wpack(const float* __restrict__ wqk,
                                                _Float16* __restrict__ wh) {
  int e = blockIdx.x * 1024 + threadIdx.x;  // 72*1024 = 73728 = 128*576
  int co = e / 576, t = e % 576;
  int ci = t / 9, rs = t % 9;
  int r = rs / 3, s = rs % 3;
  int ch = ci >> 5, t32 = ci & 31;
  wh[(((r * 2 + ch) * 128 + co) * 96) + s * 32 + t32] = (_Float16)wqk[e];
}

// ---------------- Kernel XH: zero the halo of padded xh --------------------
// per b: rows {0,193} all 196 px (2*1568 chunks) + rows 1..192 px {0,193,194,195}
// (192*32 chunks). 9280 chunks/b * 16 b = 148480 = 580*256.
__global__ __launch_bounds__(256) void k_xhalo(_Float16* __restrict__ xh) {
  int e = blockIdx.x * 256 + threadIdx.x;
  int b = e / 9280, i = e % 9280;
  int r, px, c;
  if (i < 3136) {
    r = (i < 1568) ? 0 : 193;
    int j = (i < 1568) ? i : i - 1568;
    px = j >> 3;
    c = j & 7;
  } else {
    int i2 = i - 3136;
    r = 1 + (i2 >> 5);
    int rem = i2 & 31;
    int sel = rem >> 3;
    px = (sel == 0) ? 0 : 192 + sel;  // 0,193,194,195
    c = rem & 7;
  }
  *(f16x8*)(xh + (((size_t)b * XPH + r) * XPW + px) * 64 + c * 8) =
      (f16x8)(_Float16)0;
}

// ---------------- Kernel X: x fp32 NCHW -> fp16 padded channels-last -------
// grid 16*192*3, block 256. LDS transpose tile 64ci x 64col.
__global__ __launch_bounds__(256) void k_xpack(const float* __restrict__ x,
                                               _Float16* __restrict__ xh) {
  int blk = blockIdx.x;
  int xg = blk % 3;
  int t = blk / 3;
  int y = t % 192, b = t / 192;
  int x0 = xg * 64;
  __shared__ _Float16 tl[64 * 72];  // [col][ci]
  int tid = threadIdx.x;
  int ci = tid >> 2, c4 = (tid & 3) * 16;
  const float* xp = x + ((size_t)(b * 64 + ci) * HH + y) * WW + x0 + c4;
#pragma unroll
  for (int i = 0; i < 4; ++i) {
    float4 v = *(const float4*)(xp + i * 4);
    tl[(c4 + i * 4 + 0) * 72 + ci] = (_Float16)v.x;
    tl[(c4 + i * 4 + 1) * 72 + ci] = (_Float16)v.y;
    tl[(c4 + i * 4 + 2) * 72 + ci] = (_Float16)v.z;
    tl[(c4 + i * 4 + 3) * 72 + ci] = (_Float16)v.w;
  }
  __syncthreads();
#pragma unroll
  for (int i = 0; i < 2; ++i) {
    int e = tid + 256 * i;
    int col = e >> 3, g = e & 7;
    *(f16x8*)(xh + (((size_t)b * XPH + y + 1) * XPW + x0 + 1 + col) * 64 + g * 8) =
        *(f16x8*)&tl[col * 72 + g * 8];
  }
}

// ---------------- Kernel 1: qk conv3x3 stride3, no-LDS MFMA implicit GEMM --
// grid 512 = b x pt(32); block 256. M=128 co, N=128 px (2 rows x 64).
__global__ __launch_bounds__(256) void k_qkconv(const _Float16* __restrict__ xh,
                                                const _Float16* __restrict__ wh,
                                                _Float16* __restrict__ qkh) {
  int blk = blockIdx.x;
  int pt = blk & 31, b = blk >> 5;
  int tid = threadIdx.x;
  int w = tid >> 6, lane = tid & 63, n16 = lane & 15, quad = lane >> 4;
  int mh = w & 1, nh = w >> 1;
  const _Float16* xb = xh + (size_t)b * (XPH * XPW * 64);

  f32x4 acc[4][4];
#pragma unroll
  for (int mt = 0; mt < 4; ++mt)
#pragma unroll
    for (int nt = 0; nt < 4; ++nt) acc[mt][nt] = (f32x4){0.f, 0.f, 0.f, 0.f};

#pragma unroll
  for (int kc = 0; kc < 6; ++kc) {
    int r = kc >> 1, ch = kc & 1;
    int irow = 6 * pt + 3 * nh + r;
    const _Float16* wp = wh + (size_t)kc * (128 * 96);
#pragma unroll
    for (int s = 0; s < 3; ++s) {
      f16x8 af[4], bf[4];
#pragma unroll
      for (int mt = 0; mt < 4; ++mt)
        af[mt] = *(const f16x8*)(wp + (mh * 64 + mt * 16 + n16) * 96 + s * 32 +
                                 quad * 8);
#pragma unroll
      for (int nt = 0; nt < 4; ++nt) {
        int col = 3 * (nt * 16 + n16) + s;
        bf[nt] = *(const f16x8*)(xb + ((size_t)(irow + 1) * XPW + col + 1) * 64 +
                                 ch * 32 + quad * 8);
      }
#pragma unroll
      for (int mt = 0; mt < 4; ++mt)
#pragma unroll
        for (int nt = 0; nt < 4; ++nt)
          acc[mt][nt] = __builtin_amdgcn_mfma_f32_16x16x32_f16(af[mt], bf[nt],
                                                               acc[mt][nt], 0, 0, 0);
    }
  }
  int py = pt * 2 + nh;
#pragma unroll
  for (int mt = 0; mt < 4; ++mt)
#pragma unroll
    for (int reg = 0; reg < 4; ++reg) {
      int co = mh * 64 + mt * 16 + quad * 4 + reg;
      _Float16* op = qkh + (size_t)(b * 128 + co) * HW2 + py * 64;
#pragma unroll
      for (int nt = 0; nt < 4; ++nt) op[nt * 16 + n16] = (_Float16)acc[mt][nt][reg];
    }
}

// ---------------- Kernel Q: build padded shifted q copies ------------------
// qpad[b][djx][ci][68][64]: row-pad 2, col pre-shifted by dj=djx-2, zero-fill.
__global__ __launch_bounds__(256) void k_qpad(const _Float16* __restrict__ qkh,
                                              _Float16* __restrict__ qpad) {
  int blk = blockIdx.x;  // 1024 = b*64+ci
  int b = blk >> 6, ci = blk & 63;
  __shared__ _Float16 qrow[4096];
  int tid = threadIdx.x;
  const _Float16* src = qkh + (size_t)(b * 128 + ci) * HW2;
#pragma unroll
  for (int i = 0; i < 2; ++i)
    ((f16x8*)qrow)[tid + 256 * i] = ((const f16x8*)src)[tid + 256 * i];
  __syncthreads();
  _Float16* dst = qpad + ((size_t)(b * 5) * 64 + ci) * 4352;
  for (int it = tid; it < 2720; it += 256) {
    int w8 = it & 7;
    int hr = (it >> 3) % 68;
    int djx = (it >> 3) / 68;
    int h = hr - 2;
    f16x8 v = (f16x8)(_Float16)0;
    if ((unsigned)h < 64u) {
#pragma unroll
      for (int j = 0; j < 8; ++j) {
        int c = w8 * 8 + j + djx - 2;
        if ((unsigned)c < 64u) v[j] = qrow[h * 64 + c];
      }
    }
    *(f16x8*)(dst + (size_t)djx * (64 * 4352) + hr * 64 + w8 * 8) = v;
  }
}

// ---------------- Kernel 2: attn via MFMA, atomic-merged K partials --------
// grid 800 = ((b*25+sh)<<1)|sp; block 256. 64x64 co x ci; K=2048 per part.
__global__ __launch_bounds__(256) void k_attn(const _Float16* __restrict__ qkh,
                                              const _Float16* __restrict__ qpad,
                                              float* __restrict__ attn_p) {
  int blk = blockIdx.x;
  int sp = blk & 1;
  int t = blk >> 1;
  int sh = t % 25, b = t / 25;
  int djx = sh % 5, dix = sh / 5;
  const _Float16* kb = qkh + (size_t)(b * 128 + 64) * HW2;
  const _Float16* qpb = qpad + ((size_t)(b * 5 + djx) * 64) * 4352 + dix * 64;
  __shared__ __align__(16) _Float16 ks[64 * 264];
  __shared__ __align__(16) _Float16 qs[64 * 264];
  int tid = threadIdx.x, w = tid >> 6, lane = tid & 63;
  int n16 = lane & 15, quad = lane >> 4;

  f32x4 acc[4][4];
#pragma unroll
  for (int mt = 0; mt < 4; ++mt)
#pragma unroll
    for (int nt = 0; nt < 4; ++nt) acc[mt][nt] = (f32x4){0.f, 0.f, 0.f, 0.f};

  for (int c = 0; c < 8; ++c) {
    int p0 = sp * 2048 + c * 256;
    __syncthreads();
#pragma unroll
    for (int i = 0; i < 8; ++i) {
      int e = tid + 256 * i;
      int g = e & 31, row = e >> 5;
      *(f16x8*)&ks[row * 264 + g * 8] =
          *(const f16x8*)(kb + (size_t)row * HW2 + p0 + g * 8);
      *(f16x8*)&qs[row * 264 + g * 8] =
          *(const f16x8*)(qpb + (size_t)row * 4352 + p0 + g * 8);
    }
    __syncthreads();
#pragma unroll
    for (int ki = 0; ki < 2; ++ki) {
      int ko = (w * 2 + ki) * 32 + quad * 8;
      f16x8 af[4], bf[4];
#pragma unroll
      for (int mt = 0; mt < 4; ++mt)
        af[mt] = *(const f16x8*)&ks[(mt * 16 + n16) * 264 + ko];
#pragma unroll
      for (int nt = 0; nt < 4; ++nt)
        bf[nt] = *(const f16x8*)&qs[(nt * 16 + n16) * 264 + ko];
#pragma unroll
      for (int mt = 0; mt < 4; ++mt)
#pragma unroll
        for (int nt = 0; nt < 4; ++nt)
          acc[mt][nt] = __builtin_amdgcn_mfma_f32_16x16x32_f16(af[mt], bf[nt],
                                                               acc[mt][nt], 0, 0, 0);
    }
  }
  float* racc = (float*)ks;
  __syncthreads();
  for (int e = tid; e < 64 * 66; e += 256) racc[e] = 0.f;
  __syncthreads();
#pragma unroll
  for (int mt = 0; mt < 4; ++mt) {
    int co = mt * 16 + quad * 4;
#pragma unroll
    for (int reg = 0; reg < 4; ++reg)
#pragma unroll
      for (int nt = 0; nt < 4; ++nt)
        atomicAdd(&racc[(co + reg) * 66 + nt * 16 + n16], acc[mt][nt][reg]);
  }
  __syncthreads();
  float* op = attn_p + (size_t)(b * 25 + sh) * 4096;
  for (int e = tid; e < 4096; e += 256)
    atomicAdd(&op[e], racc[(e >> 6) * 66 + (e & 63)]);
}

// ---------------- Kernel 3: ak_t = valid-conv(attn, weight) ----------------
__global__ __launch_bounds__(576) void k_akconv(const float* __restrict__ attn_p,
                                                const float* __restrict__ wgt,
                                                float* __restrict__ akt) {
  int blk = blockIdx.x;
  int b = blk >> 6, co = blk & 63;
  __shared__ float sa[64 * 25];
  int tid = threadIdx.x;
  for (int e = tid; e < 1600; e += 576) {
    int didj = e >> 6, ci = e & 63;
    size_t idx = (((size_t)b * 25 + didj) * 64 + co) * 64 + ci;
    sa[ci * 25 + didj] = attn_p[idx];
  }
  __syncthreads();
  int o = tid / 9, rs = tid % 9;
  int ki = rs / 3, kj = rs % 3;
  float acc = 0.f;
  for (int ci = 0; ci < 64; ++ci) {
    const float* wp = wgt + (o * 64 + ci) * 9;
    const float* ap = sa + ci * 25 + ki * 5 + kj;
#pragma unroll
    for (int r = 0; r < 3; ++r)
#pragma unroll
      for (int s = 0; s < 3; ++s) acc += ap[r * 5 + s] * wp[r * 3 + s];
  }
  akt[((size_t)(b * 64 + o) * 64 + co) * 9 + rs] = acc;
}

// ---------------- Kernel 4: per-(b,o) norm + fp16 kern assembly ------------
__global__ __launch_bounds__(576) void k_kern(const float* __restrict__ akt,
                                              const float* __restrict__ wgt,
                                              const float* __restrict__ temp,
                                              _Float16* __restrict__ kh) {
  int blk = blockIdx.x;
  int o = blk & 63;
  int tid = threadIdx.x;
  float v = akt[(size_t)blk * 576 + tid];
  float sq = v * v;
#pragma unroll
  for (int m = 1; m < 64; m <<= 1) sq += __shfl_xor(sq, m, 64);
  __shared__ float wsum[9];
  if ((tid & 63) == 0) wsum[tid >> 6] = sq;
  __syncthreads();
  float tot = 0.f;
#pragma unroll
  for (int i = 0; i < 9; ++i) tot += wsum[i];
  float inv = temp[0] / fmaxf(sqrtf(tot), 1e-12f);
  float kv = wgt[o * 576 + tid] + v * inv;
  int b = blk >> 6;
  int ci = tid / 9, rs = tid % 9;
  kh[(((size_t)(b * 9 + rs) * 64 + o) * 64) + ci] = (_Float16)kv;
}

// ---------------- Kernel 5: dynamic 3x3 conv + ReLU, LDS-staged x tile -----
// grid 2304 = b x yt(48) x xt(3); block 256 (4 waves, wave = one y-row).
// Stage the 6-row x 68-px x 64-ci padded x tile ONCE into LDS (XOR-swizzled
// chunks so the px-stride-128B reads are conflict-free), then all 18x16
// MFMAs/wave read B-frags from LDS. A-frags from kh (L2-hot).
__global__ __launch_bounds__(256) void k_final(const _Float16* __restrict__ xh,
                                               const _Float16* __restrict__ kh,
                                               float* __restrict__ out) {
  int blk = blockIdx.x;
  int xt = blk % 3;
  int t2 = blk / 3;
  int yt = t2 % 48, b = t2 / 48;
  int y0 = yt * 4, x0 = xt * 64;

  __shared__ __align__(16) _Float16 xs[6 * 68 * 64];  // 52,224 B -> 3 blocks/CU

  int tid = threadIdx.x;
  int w = tid >> 6, lane = tid & 63;
  int n16 = lane & 15, quad = lane >> 4;

  const _Float16* xb = xh + (size_t)b * (XPH * XPW * 64);
  const _Float16* kb = kh + (size_t)b * (9 * 64 * 64);

  // ---- stage: 6 rows (padded y0..y0+5) x 68 px (padded x0..x0+67), all in
  // bounds thanks to the halo. 3264 16B-chunks; issue all loads, then write.
  {
    f16x8 v[13];
#pragma unroll
    for (int i = 0; i < 13; ++i) {
      int e = tid + 256 * i;
      if (e < 3264) {
        int row = e / 544, rem = e % 544;
        int px = rem >> 3, c = rem & 7;
        v[i] = *(const f16x8*)(xb + ((size_t)(y0 + row) * XPW + x0 + px) * 64 +
                               c * 8);
      }
    }
#pragma unroll
    for (int i = 0; i < 13; ++i) {
      int e = tid + 256 * i;
      if (e < 3264) {
        int row = e / 544, rem = e % 544;
        int px = rem >> 3, c = rem & 7;
        // swizzle: permute 16B chunks within each px's 128B frame by px&7
        *(f16x8*)&xs[((row * 68 + px) * 8 + (c ^ (px & 7))) * 8] = v[i];
      }
    }
  }
  __syncthreads();

  f32x4 acc[4][4];
#pragma unroll
  for (int mt = 0; mt < 4; ++mt)
#pragma unroll
    for (int nt = 0; nt < 4; ++nt) acc[mt][nt] = (f32x4){0.f, 0.f, 0.f, 0.f};

#pragma unroll
  for (int ch = 0; ch < 18; ++ch) {
    int rs = ch >> 1, hi = ch & 1;
    int r = rs / 3, s = rs % 3;
    int trow = w + r;  // tile row 0..5
    f16x8 af[4], bf[4];
#pragma unroll
    for (int mt = 0; mt < 4; ++mt)
      af[mt] = *(const f16x8*)(kb + ((size_t)rs * 64 + mt * 16 + n16) * 64 +
                               hi * 32 + quad * 8);
#pragma unroll
    for (int nt = 0; nt < 4; ++nt) {
      int px = nt * 16 + n16 + s;  // 0..65
      int c = (hi * 4 + quad) ^ (px & 7);
      bf[nt] = *(const f16x8*)&xs[((trow * 68 + px) * 8 + c) * 8];
    }
#pragma unroll
    for (int mt = 0; mt < 4; ++mt)
#pragma unroll
      for (int nt = 0; nt < 4; ++nt)
        acc[mt][nt] = __builtin_amdgcn_mfma_f32_16x16x32_f16(af[mt], bf[nt],
                                                             acc[mt][nt], 0, 0, 0);
  }

  int y = y0 + w;
#pragma unroll
  for (int mt = 0; mt < 4; ++mt)
#pragma unroll
    for (int reg = 0; reg < 4; ++reg) {
      int o = mt * 16 + quad * 4 + reg;
      float* op = out + (((size_t)(b * 64 + o) * HH + y) * WW + x0);
#pragma unroll
      for (int nt = 0; nt < 4; ++nt)
        op[nt * 16 + n16] = fmaxf(acc[mt][nt][reg], 0.f);
    }
}

extern "C" void kernel_launch(void* const* d_in, const int* in_sizes, int n_in,
                              void* d_out, int out_size, void* d_ws, size_t ws_size,
                              hipStream_t stream) {
  const float* x = (const float*)d_in[0];     // (16,64,192,192)
  const float* wqk = (const float*)d_in[1];   // (128,64,3,3)
  const float* wgt = (const float*)d_in[2];   // (64,64,3,3)
  const float* temp = (const float*)d_in[3];  // (1,1,1)
  float* out = (float*)d_out;
  char* ws = (char*)d_ws;

  // Workspace layout (bytes):
  _Float16* xh = (_Float16*)ws;                        // 77,873,152 (16*194*196*64*2)
  _Float16* qkh = (_Float16*)(ws + 77873152);          // 16,777,216
  _Float16* qpad = (_Float16*)(ws + 94650368);         // 44,564,480
  float* attn_p = (float*)(ws + 139214848);            //  6,553,600 (single, atomic-merged)
  // wh aliases the qpad tail: dead before k_qpad writes qpad.
  _Float16* wh = (_Float16*)(ws + 139067392);          //    147,456
  // akt/kh alias the qpad head (qpad dead after k_attn):
  float* akt = (float*)(ws + 94650368);                //  2,359,296
  _Float16* kh = (_Float16*)(ws + 97009664);           //  1,179,648
  // total 145,768,448 B (~145.8 MB, < previous 150.1 MB)

  hipMemsetAsync(attn_p, 0, 6553600, stream);
  k_wpack<<<dim3(72), 1024, 0, stream>>>(wqk, wh);
  k_xhalo<<<dim3(580), 256, 0, stream>>>(xh);
  k_xpack<<<dim3(9216), 256, 0, stream>>>(x, xh);
  k_qkconv<<<dim3(512), 256, 0, stream>>>(xh, wh, qkh);
  k_qpad<<<dim3(1024), 256, 0, stream>>>(qkh, qpad);
  k_attn<<<dim3(800), 256, 0, stream>>>(qkh, qpad, attn_p);
  k_akconv<<<dim3(1024), 576, 0, stream>>>(attn_p, wgt, akt);
  k_kern<<<dim3(1024), 576, 0, stream>>>(akt, wgt, temp, kh);
  k_final<<<dim3(2304), 256, 0, stream>>>(xh, kh, out);
}

// Round 2
// 602.696 us; speedup vs baseline: 1.0970x; 1.0104x over previous
//
#include <hip/hip_runtime.h>
#include <cstddef>

#define BB 16
#define CC_ 64
#define HH 192
#define WW 192
#define HW2 4096
// padded channels-last x: [b][194][196][64], real data at rows 1..192, cols 1..192
#define XPH 194
#define XPW 196

typedef _Float16 f16x8 __attribute__((ext_vector_type(8)));
typedef float f32x4 __attribute__((ext_vector_type(4)));

// ---------------- Kernel W: pack wqk fp32 -> fp16 A-fragment layout --------
// wh[kc=(r*2+cihalf)][co 128][s*32 + ci%32]
__global__ __launch_bounds__(1024) void k_wpack(const float* __restrict__ wqk,
                                                _Float16* __restrict__ wh) {
  int e = blockIdx.x * 1024 + threadIdx.x;  // 72*1024 = 73728 = 128*576
  int co = e / 576, t = e % 576;
  int ci = t / 9, rs = t % 9;
  int r = rs / 3, s = rs % 3;
  int ch = ci >> 5, t32 = ci & 31;
  wh[(((r * 2 + ch) * 128 + co) * 96) + s * 32 + t32] = (_Float16)wqk[e];
}

// ---------------- Kernel XH: zero the halo of padded xh --------------------
__global__ __launch_bounds__(256) void k_xhalo(_Float16* __restrict__ xh) {
  int e = blockIdx.x * 256 + threadIdx.x;
  int b = e / 9280, i = e % 9280;
  int r, px, c;
  if (i < 3136) {
    r = (i < 1568) ? 0 : 193;
    int j = (i < 1568) ? i : i - 1568;
    px = j >> 3;
    c = j & 7;
  } else {
    int i2 = i - 3136;
    r = 1 + (i2 >> 5);
    int rem = i2 & 31;
    int sel = rem >> 3;
    px = (sel == 0) ? 0 : 192 + sel;  // 0,193,194,195
    c = rem & 7;
  }
  *(f16x8*)(xh + (((size_t)b * XPH + r) * XPW + px) * 64 + c * 8) =
      (f16x8)(_Float16)0;
}

// ---------------- Kernel X: x fp32 NCHW -> fp16 padded channels-last -------
__global__ __launch_bounds__(256) void k_xpack(const float* __restrict__ x,
                                               _Float16* __restrict__ xh) {
  int blk = blockIdx.x;
  int xg = blk % 3;
  int t = blk / 3;
  int y = t % 192, b = t / 192;
  int x0 = xg * 64;
  __shared__ _Float16 tl[64 * 72];  // [col][ci]
  int tid = threadIdx.x;
  int ci = tid >> 2, c4 = (tid & 3) * 16;
  const float* xp = x + ((size_t)(b * 64 + ci) * HH + y) * WW + x0 + c4;
#pragma unroll
  for (int i = 0; i < 4; ++i) {
    float4 v = *(const float4*)(xp + i * 4);
    tl[(c4 + i * 4 + 0) * 72 + ci] = (_Float16)v.x;
    tl[(c4 + i * 4 + 1) * 72 + ci] = (_Float16)v.y;
    tl[(c4 + i * 4 + 2) * 72 + ci] = (_Float16)v.z;
    tl[(c4 + i * 4 + 3) * 72 + ci] = (_Float16)v.w;
  }
  __syncthreads();
#pragma unroll
  for (int i = 0; i < 2; ++i) {
    int e = tid + 256 * i;
    int col = e >> 3, g = e & 7;
    *(f16x8*)(xh + (((size_t)b * XPH + y + 1) * XPW + x0 + 1 + col) * 64 + g * 8) =
        *(f16x8*)&tl[col * 72 + g * 8];
  }
}

// ---------------- Kernel 1: qk conv3x3 stride3, no-LDS MFMA implicit GEMM --
__global__ __launch_bounds__(256) void k_qkconv(const _Float16* __restrict__ xh,
                                                const _Float16* __restrict__ wh,
                                                _Float16* __restrict__ qkh) {
  int blk = blockIdx.x;
  int pt = blk & 31, b = blk >> 5;
  int tid = threadIdx.x;
  int w = tid >> 6, lane = tid & 63, n16 = lane & 15, quad = lane >> 4;
  int mh = w & 1, nh = w >> 1;
  const _Float16* xb = xh + (size_t)b * (XPH * XPW * 64);

  f32x4 acc[4][4];
#pragma unroll
  for (int mt = 0; mt < 4; ++mt)
#pragma unroll
    for (int nt = 0; nt < 4; ++nt) acc[mt][nt] = (f32x4){0.f, 0.f, 0.f, 0.f};

#pragma unroll
  for (int kc = 0; kc < 6; ++kc) {
    int r = kc >> 1, ch = kc & 1;
    int irow = 6 * pt + 3 * nh + r;
    const _Float16* wp = wh + (size_t)kc * (128 * 96);
#pragma unroll
    for (int s = 0; s < 3; ++s) {
      f16x8 af[4], bf[4];
#pragma unroll
      for (int mt = 0; mt < 4; ++mt)
        af[mt] = *(const f16x8*)(wp + (mh * 64 + mt * 16 + n16) * 96 + s * 32 +
                                 quad * 8);
#pragma unroll
      for (int nt = 0; nt < 4; ++nt) {
        int col = 3 * (nt * 16 + n16) + s;
        bf[nt] = *(const f16x8*)(xb + ((size_t)(irow + 1) * XPW + col + 1) * 64 +
                                 ch * 32 + quad * 8);
      }
#pragma unroll
      for (int mt = 0; mt < 4; ++mt)
#pragma unroll
        for (int nt = 0; nt < 4; ++nt)
          acc[mt][nt] = __builtin_amdgcn_mfma_f32_16x16x32_f16(af[mt], bf[nt],
                                                               acc[mt][nt], 0, 0, 0);
    }
  }
  int py = pt * 2 + nh;
#pragma unroll
  for (int mt = 0; mt < 4; ++mt)
#pragma unroll
    for (int reg = 0; reg < 4; ++reg) {
      int co = mh * 64 + mt * 16 + quad * 4 + reg;
      _Float16* op = qkh + (size_t)(b * 128 + co) * HW2 + py * 64;
#pragma unroll
      for (int nt = 0; nt < 4; ++nt) op[nt * 16 + n16] = (_Float16)acc[mt][nt][reg];
    }
}

// ---------------- Kernel Q: build padded shifted q copies ------------------
// qpad[b][djx][ci][68][64]: row-pad 2, col pre-shifted by dj=djx-2, zero-fill.
// Vectorized: per (row,w8) read 3 aligned f16x8 from LDS, emit all 5 djx
// shifts via compile-time element selection (no scalar LDS gathers).
__global__ __launch_bounds__(256) void k_qpad(const _Float16* __restrict__ qkh,
                                              _Float16* __restrict__ qpad) {
  int blk = blockIdx.x;  // 1024 = b*64+ci
  int b = blk >> 6, ci = blk & 63;
  __shared__ _Float16 qrow[4096];
  int tid = threadIdx.x;
  const _Float16* src = qkh + (size_t)(b * 128 + ci) * HW2;
#pragma unroll
  for (int i = 0; i < 2; ++i)
    ((f16x8*)qrow)[tid + 256 * i] = ((const f16x8*)src)[tid + 256 * i];
  __syncthreads();
  _Float16* dst = qpad + ((size_t)(b * 5) * 64 + ci) * 4352;
  const f16x8 zero = (f16x8)(_Float16)0;
  for (int it = tid; it < 544; it += 256) {  // 68 rows x 8 w8
    int w8 = it & 7, hr = it >> 3;
    int h = hr - 2;
    bool rowok = (unsigned)h < 64u;
    f16x8 vm = (rowok && w8 > 0) ? *(const f16x8*)&qrow[h * 64 + w8 * 8 - 8] : zero;
    f16x8 vc = rowok ? *(const f16x8*)&qrow[h * 64 + w8 * 8] : zero;
    f16x8 vp = (rowok && w8 < 7) ? *(const f16x8*)&qrow[h * 64 + w8 * 8 + 8] : zero;
#pragma unroll
    for (int djx = 0; djx < 5; ++djx) {
      const int s = djx - 2;
      f16x8 r;
#pragma unroll
      for (int j = 0; j < 8; ++j) {
        const int rel = j + s;
        r[j] = (rel < 0) ? vm[8 + rel] : ((rel < 8) ? vc[rel] : vp[rel - 8]);
      }
      *(f16x8*)(dst + (size_t)djx * (64 * 4352) + hr * 64 + w8 * 8) = r;
    }
  }
}

// ---------------- Kernel 2: attn via MFMA, no-LDS direct global->reg -------
// grid 800 = XCD-swizzled (b, sh, sp); block 256 (4 waves). 64x64 co x ci.
// Waves take contiguous K=512 slices straight from global (zero cross-wave
// reuse made LDS staging pure overhead); same-b blocks pinned to one XCD so
// k (512KB) + qpad plane (2.8MB) stay L2-resident.
__global__ __launch_bounds__(256) void k_attn(const _Float16* __restrict__ qkh,
                                              const _Float16* __restrict__ qpad,
                                              float* __restrict__ attn_p) {
  int blk = blockIdx.x;
  int xcd = blk & 7, j = blk >> 3;  // j 0..99
  int b = xcd + ((j >= 50) ? 8 : 0);
  int t = (j >= 50) ? (j - 50) : j;  // 0..49
  int sh = t >> 1, sp = t & 1;
  int djx = sh % 5, dix = sh / 5;
  const _Float16* kb = qkh + (size_t)(b * 128 + 64) * HW2;
  const _Float16* qpb = qpad + ((size_t)(b * 5 + djx) * 64) * 4352 + dix * 64;
  int tid = threadIdx.x, w = tid >> 6, lane = tid & 63;
  int n16 = lane & 15, quad = lane >> 4;

  __shared__ float racc[64 * 66];
  for (int e = tid; e < 64 * 66; e += 256) racc[e] = 0.f;
  __syncthreads();

  f32x4 acc[4][4];
#pragma unroll
  for (int mt = 0; mt < 4; ++mt)
#pragma unroll
    for (int nt = 0; nt < 4; ++nt) acc[mt][nt] = (f32x4){0.f, 0.f, 0.f, 0.f};

  int base = sp * 2048 + w * 512 + quad * 8;
#pragma unroll 4
  for (int ks = 0; ks < 16; ++ks) {
    int p0 = base + ks * 32;
    f16x8 af[4], bf[4];
#pragma unroll
    for (int mt = 0; mt < 4; ++mt)
      af[mt] = *(const f16x8*)(kb + (size_t)(mt * 16 + n16) * HW2 + p0);
#pragma unroll
    for (int nt = 0; nt < 4; ++nt)
      bf[nt] = *(const f16x8*)(qpb + (size_t)(nt * 16 + n16) * 4352 + p0);
#pragma unroll
    for (int mt = 0; mt < 4; ++mt)
#pragma unroll
      for (int nt = 0; nt < 4; ++nt)
        acc[mt][nt] = __builtin_amdgcn_mfma_f32_16x16x32_f16(af[mt], bf[nt],
                                                             acc[mt][nt], 0, 0, 0);
  }

#pragma unroll
  for (int mt = 0; mt < 4; ++mt) {
    int co = mt * 16 + quad * 4;
#pragma unroll
    for (int reg = 0; reg < 4; ++reg)
#pragma unroll
      for (int nt = 0; nt < 4; ++nt)
        atomicAdd(&racc[(co + reg) * 66 + nt * 16 + n16], acc[mt][nt][reg]);
  }
  __syncthreads();
  float* op = attn_p + (size_t)(b * 25 + sh) * 4096;
  for (int e = tid; e < 4096; e += 256)
    atomicAdd(&op[e], racc[(e >> 6) * 66 + (e & 63)]);
}

// ---------------- Kernel 3: ak_t = valid-conv(attn, weight) ----------------
__global__ __launch_bounds__(576) void k_akconv(const float* __restrict__ attn_p,
                                                const float* __restrict__ wgt,
                                                float* __restrict__ akt) {
  int blk = blockIdx.x;
  int b = blk >> 6, co = blk & 63;
  __shared__ float sa[64 * 25];
  int tid = threadIdx.x;
  for (int e = tid; e < 1600; e += 576) {
    int didj = e >> 6, ci = e & 63;
    size_t idx = (((size_t)b * 25 + didj) * 64 + co) * 64 + ci;
    sa[ci * 25 + didj] = attn_p[idx];
  }
  __syncthreads();
  int o = tid / 9, rs = tid % 9;
  int ki = rs / 3, kj = rs % 3;
  float acc = 0.f;
  for (int ci = 0; ci < 64; ++ci) {
    const float* wp = wgt + (o * 64 + ci) * 9;
    const float* ap = sa + ci * 25 + ki * 5 + kj;
#pragma unroll
    for (int r = 0; r < 3; ++r)
#pragma unroll
      for (int s = 0; s < 3; ++s) acc += ap[r * 5 + s] * wp[r * 3 + s];
  }
  akt[((size_t)(b * 64 + o) * 64 + co) * 9 + rs] = acc;
}

// ---------------- Kernel 4: per-(b,o) norm + fp16 kern assembly ------------
__global__ __launch_bounds__(576) void k_kern(const float* __restrict__ akt,
                                              const float* __restrict__ wgt,
                                              const float* __restrict__ temp,
                                              _Float16* __restrict__ kh) {
  int blk = blockIdx.x;
  int o = blk & 63;
  int tid = threadIdx.x;
  float v = akt[(size_t)blk * 576 + tid];
  float sq = v * v;
#pragma unroll
  for (int m = 1; m < 64; m <<= 1) sq += __shfl_xor(sq, m, 64);
  __shared__ float wsum[9];
  if ((tid & 63) == 0) wsum[tid >> 6] = sq;
  __syncthreads();
  float tot = 0.f;
#pragma unroll
  for (int i = 0; i < 9; ++i) tot += wsum[i];
  float inv = temp[0] / fmaxf(sqrtf(tot), 1e-12f);
  float kv = wgt[o * 576 + tid] + v * inv;
  int b = blk >> 6;
  int ci = tid / 9, rs = tid % 9;
  kh[(((size_t)(b * 9 + rs) * 64 + o) * 64) + ci] = (_Float16)kv;
}

// ---------------- Kernel 5: dynamic 3x3 conv + ReLU, LDS-staged x tile -----
// grid 2304 = b x yt(48) x xt(3); block 256 (4 waves, wave = one y-row).
// xs staged once (XOR-swizzled, conflict-free); af (kh, L2-hot) prefetched
// 2 iterations deep via 3-buffer rotation to hide ~200cy L2 latency.
__global__ __launch_bounds__(256, 3) void k_final(const _Float16* __restrict__ xh,
                                                  const _Float16* __restrict__ kh,
                                                  float* __restrict__ out) {
  int blk = blockIdx.x;
  int xt = blk % 3;
  int t2 = blk / 3;
  int yt = t2 % 48, b = t2 / 48;
  int y0 = yt * 4, x0 = xt * 64;

  __shared__ __align__(16) _Float16 xs[6 * 68 * 64];  // 52,224 B -> 3 blocks/CU

  int tid = threadIdx.x;
  int w = tid >> 6, lane = tid & 63;
  int n16 = lane & 15, quad = lane >> 4;

  const _Float16* xb = xh + (size_t)b * (XPH * XPW * 64);
  const _Float16* kb = kh + (size_t)b * (9 * 64 * 64);

  // ---- stage: 6 rows x 68 px x 64 ci, all in bounds thanks to the halo.
  {
    f16x8 v[13];
#pragma unroll
    for (int i = 0; i < 13; ++i) {
      int e = tid + 256 * i;
      if (e < 3264) {
        int row = e / 544, rem = e % 544;
        int px = rem >> 3, c = rem & 7;
        v[i] = *(const f16x8*)(xb + ((size_t)(y0 + row) * XPW + x0 + px) * 64 +
                               c * 8);
      }
    }
#pragma unroll
    for (int i = 0; i < 13; ++i) {
      int e = tid + 256 * i;
      if (e < 3264) {
        int row = e / 544, rem = e % 544;
        int px = rem >> 3, c = rem & 7;
        *(f16x8*)&xs[((row * 68 + px) * 8 + (c ^ (px & 7))) * 8] = v[i];
      }
    }
  }
  __syncthreads();

  f32x4 acc[4][4];
#pragma unroll
  for (int mt = 0; mt < 4; ++mt)
#pragma unroll
    for (int nt = 0; nt < 4; ++nt) acc[mt][nt] = (f32x4){0.f, 0.f, 0.f, 0.f};

#define LDAF(dst, ch_)                                                          \
  {                                                                             \
    const int rs_ = (ch_) >> 1, hi_ = (ch_)&1;                                  \
    _Pragma("unroll") for (int mt = 0; mt < 4; ++mt) dst[mt] =                  \
        *(const f16x8*)(kb + ((size_t)rs_ * 64 + mt * 16 + n16) * 64 +          \
                        hi_ * 32 + quad * 8);                                   \
  }

  f16x8 af[3][4];
  LDAF(af[0], 0)
  LDAF(af[1], 1)

#pragma unroll
  for (int ch = 0; ch < 18; ++ch) {
    if (ch + 2 < 18) LDAF(af[(ch + 2) % 3], ch + 2)
    int rs = ch >> 1, hi = ch & 1;
    int r = rs / 3, s = rs % 3;
    int trow = w + r;  // tile row 0..5
    f16x8 bf[4];
#pragma unroll
    for (int nt = 0; nt < 4; ++nt) {
      int px = nt * 16 + n16 + s;  // 0..65
      int c = (hi * 4 + quad) ^ (px & 7);
      bf[nt] = *(const f16x8*)&xs[((trow * 68 + px) * 8 + c) * 8];
    }
#pragma unroll
    for (int mt = 0; mt < 4; ++mt)
#pragma unroll
      for (int nt = 0; nt < 4; ++nt)
        acc[mt][nt] = __builtin_amdgcn_mfma_f32_16x16x32_f16(af[ch % 3][mt],
                                                             bf[nt], acc[mt][nt],
                                                             0, 0, 0);
  }
#undef LDAF

  int y = y0 + w;
#pragma unroll
  for (int mt = 0; mt < 4; ++mt)
#pragma unroll
    for (int reg = 0; reg < 4; ++reg) {
      int o = mt * 16 + quad * 4 + reg;
      float* op = out + (((size_t)(b * 64 + o) * HH + y) * WW + x0);
#pragma unroll
      for (int nt = 0; nt < 4; ++nt)
        op[nt * 16 + n16] = fmaxf(acc[mt][nt][reg], 0.f);
    }
}

extern "C" void kernel_launch(void* const* d_in, const int* in_sizes, int n_in,
                              void* d_out, int out_size, void* d_ws, size_t ws_size,
                              hipStream_t stream) {
  const float* x = (const float*)d_in[0];     // (16,64,192,192)
  const float* wqk = (const float*)d_in[1];   // (128,64,3,3)
  const float* wgt = (const float*)d_in[2];   // (64,64,3,3)
  const float* temp = (const float*)d_in[3];  // (1,1,1)
  float* out = (float*)d_out;
  char* ws = (char*)d_ws;

  // Workspace layout (bytes):
  _Float16* xh = (_Float16*)ws;                        // 77,873,152 (16*194*196*64*2)
  _Float16* qkh = (_Float16*)(ws + 77873152);          // 16,777,216
  _Float16* qpad = (_Float16*)(ws + 94650368);         // 44,564,480
  float* attn_p = (float*)(ws + 139214848);            //  6,553,600 (single, atomic-merged)
  // wh aliases the qpad tail: dead before k_qpad writes qpad.
  _Float16* wh = (_Float16*)(ws + 139067392);          //    147,456
  // akt/kh alias the qpad head (qpad dead after k_attn):
  float* akt = (float*)(ws + 94650368);                //  2,359,296
  _Float16* kh = (_Float16*)(ws + 97009664);           //  1,179,648
  // total 145,768,448 B (~145.8 MB)

  hipMemsetAsync(attn_p, 0, 6553600, stream);
  k_wpack<<<dim3(72), 1024, 0, stream>>>(wqk, wh);
  k_xhalo<<<dim3(580), 256, 0, stream>>>(xh);
  k_xpack<<<dim3(9216), 256, 0, stream>>>(x, xh);
  k_qkconv<<<dim3(512), 256, 0, stream>>>(xh, wh, qkh);
  k_qpad<<<dim3(1024), 256, 0, stream>>>(qkh, qpad);
  k_attn<<<dim3(800), 256, 0, stream>>>(qkh, qpad, attn_p);
  k_akconv<<<dim3(1024), 576, 0, stream>>>(attn_p, wgt, akt);
  k_kern<<<dim3(1024), 576, 0, stream>>>(akt, wgt, temp, kh);
  k_final<<<dim3(2304), 256, 0, stream>>>(xh, kh, out);
}

// Round 3
// 591.144 us; speedup vs baseline: 1.1185x; 1.0195x over previous
//
#include <hip/hip_runtime.h>
#include <cstddef>

#define BB 16
#define CC_ 64
#define HH 192
#define WW 192
#define HW2 4096
// padded channels-last x: [b][194][196][64], real data at rows 1..192, cols 1..192
#define XPH 194
#define XPW 196

typedef _Float16 f16x8 __attribute__((ext_vector_type(8)));
typedef float f32x4 __attribute__((ext_vector_type(4)));

// ---------------- Kernel W: pack wqk fp32 -> fp16 A-fragment layout --------
// wh[kc=(r*2+cihalf)][co 128][s*32 + ci%32]
__global__ __launch_bounds__(1024) void k_wpack(const float* __restrict__ wqk,
                                                _Float16* __restrict__ wh) {
  int e = blockIdx.x * 1024 + threadIdx.x;  // 72*1024 = 73728 = 128*576
  int co = e / 576, t = e % 576;
  int ci = t / 9, rs = t % 9;
  int r = rs / 3, s = rs % 3;
  int ch = ci >> 5, t32 = ci & 31;
  wh[(((r * 2 + ch) * 128 + co) * 96) + s * 32 + t32] = (_Float16)wqk[e];
}

// ---------------- Kernel XH: zero the halo of padded xh --------------------
__global__ __launch_bounds__(256) void k_xhalo(_Float16* __restrict__ xh) {
  int e = blockIdx.x * 256 + threadIdx.x;
  int b = e / 9280, i = e % 9280;
  int r, px, c;
  if (i < 3136) {
    r = (i < 1568) ? 0 : 193;
    int j = (i < 1568) ? i : i - 1568;
    px = j >> 3;
    c = j & 7;
  } else {
    int i2 = i - 3136;
    r = 1 + (i2 >> 5);
    int rem = i2 & 31;
    int sel = rem >> 3;
    px = (sel == 0) ? 0 : 192 + sel;  // 0,193,194,195
    c = rem & 7;
  }
  *(f16x8*)(xh + (((size_t)b * XPH + r) * XPW + px) * 64 + c * 8) =
      (f16x8)(_Float16)0;
}

// ---------------- Kernel X: x fp32 NCHW -> fp16 padded channels-last -------
__global__ __launch_bounds__(256) void k_xpack(const float* __restrict__ x,
                                               _Float16* __restrict__ xh) {
  int blk = blockIdx.x;
  int xg = blk % 3;
  int t = blk / 3;
  int y = t % 192, b = t / 192;
  int x0 = xg * 64;
  __shared__ _Float16 tl[64 * 72];  // [col][ci]
  int tid = threadIdx.x;
  int ci = tid >> 2, c4 = (tid & 3) * 16;
  const float* xp = x + ((size_t)(b * 64 + ci) * HH + y) * WW + x0 + c4;
#pragma unroll
  for (int i = 0; i < 4; ++i) {
    float4 v = *(const float4*)(xp + i * 4);
    tl[(c4 + i * 4 + 0) * 72 + ci] = (_Float16)v.x;
    tl[(c4 + i * 4 + 1) * 72 + ci] = (_Float16)v.y;
    tl[(c4 + i * 4 + 2) * 72 + ci] = (_Float16)v.z;
    tl[(c4 + i * 4 + 3) * 72 + ci] = (_Float16)v.w;
  }
  __syncthreads();
#pragma unroll
  for (int i = 0; i < 2; ++i) {
    int e = tid + 256 * i;
    int col = e >> 3, g = e & 7;
    *(f16x8*)(xh + (((size_t)b * XPH + y + 1) * XPW + x0 + 1 + col) * 64 + g * 8) =
        *(f16x8*)&tl[col * 72 + g * 8];
  }
}

// ---------------- Kernel 1: qk conv3x3 stride3, no-LDS MFMA implicit GEMM --
__global__ __launch_bounds__(256) void k_qkconv(const _Float16* __restrict__ xh,
                                                const _Float16* __restrict__ wh,
                                                _Float16* __restrict__ qkh) {
  int blk = blockIdx.x;
  int pt = blk & 31, b = blk >> 5;
  int tid = threadIdx.x;
  int w = tid >> 6, lane = tid & 63, n16 = lane & 15, quad = lane >> 4;
  int mh = w & 1, nh = w >> 1;
  const _Float16* xb = xh + (size_t)b * (XPH * XPW * 64);

  f32x4 acc[4][4];
#pragma unroll
  for (int mt = 0; mt < 4; ++mt)
#pragma unroll
    for (int nt = 0; nt < 4; ++nt) acc[mt][nt] = (f32x4){0.f, 0.f, 0.f, 0.f};

#pragma unroll
  for (int kc = 0; kc < 6; ++kc) {
    int r = kc >> 1, ch = kc & 1;
    int irow = 6 * pt + 3 * nh + r;
    const _Float16* wp = wh + (size_t)kc * (128 * 96);
#pragma unroll
    for (int s = 0; s < 3; ++s) {
      f16x8 af[4], bf[4];
#pragma unroll
      for (int mt = 0; mt < 4; ++mt)
        af[mt] = *(const f16x8*)(wp + (mh * 64 + mt * 16 + n16) * 96 + s * 32 +
                                 quad * 8);
#pragma unroll
      for (int nt = 0; nt < 4; ++nt) {
        int col = 3 * (nt * 16 + n16) + s;
        bf[nt] = *(const f16x8*)(xb + ((size_t)(irow + 1) * XPW + col + 1) * 64 +
                                 ch * 32 + quad * 8);
      }
#pragma unroll
      for (int mt = 0; mt < 4; ++mt)
#pragma unroll
        for (int nt = 0; nt < 4; ++nt)
          acc[mt][nt] = __builtin_amdgcn_mfma_f32_16x16x32_f16(af[mt], bf[nt],
                                                               acc[mt][nt], 0, 0, 0);
    }
  }
  int py = pt * 2 + nh;
#pragma unroll
  for (int mt = 0; mt < 4; ++mt)
#pragma unroll
    for (int reg = 0; reg < 4; ++reg) {
      int co = mh * 64 + mt * 16 + quad * 4 + reg;
      _Float16* op = qkh + (size_t)(b * 128 + co) * HW2 + py * 64;
#pragma unroll
      for (int nt = 0; nt < 4; ++nt) op[nt * 16 + n16] = (_Float16)acc[mt][nt][reg];
    }
}

// ---------------- Kernel Q: build padded shifted q copies ------------------
// qpad[b][djx][ci][68][64]: row-pad 2, col pre-shifted by dj=djx-2, zero-fill.
__global__ __launch_bounds__(256) void k_qpad(const _Float16* __restrict__ qkh,
                                              _Float16* __restrict__ qpad) {
  int blk = blockIdx.x;  // 1024 = b*64+ci
  int b = blk >> 6, ci = blk & 63;
  __shared__ _Float16 qrow[4096];
  int tid = threadIdx.x;
  const _Float16* src = qkh + (size_t)(b * 128 + ci) * HW2;
#pragma unroll
  for (int i = 0; i < 2; ++i)
    ((f16x8*)qrow)[tid + 256 * i] = ((const f16x8*)src)[tid + 256 * i];
  __syncthreads();
  _Float16* dst = qpad + ((size_t)(b * 5) * 64 + ci) * 4352;
  const f16x8 zero = (f16x8)(_Float16)0;
  for (int it = tid; it < 544; it += 256) {  // 68 rows x 8 w8
    int w8 = it & 7, hr = it >> 3;
    int h = hr - 2;
    bool rowok = (unsigned)h < 64u;
    f16x8 vm = (rowok && w8 > 0) ? *(const f16x8*)&qrow[h * 64 + w8 * 8 - 8] : zero;
    f16x8 vc = rowok ? *(const f16x8*)&qrow[h * 64 + w8 * 8] : zero;
    f16x8 vp = (rowok && w8 < 7) ? *(const f16x8*)&qrow[h * 64 + w8 * 8 + 8] : zero;
#pragma unroll
    for (int djx = 0; djx < 5; ++djx) {
      const int s = djx - 2;
      f16x8 r;
#pragma unroll
      for (int j = 0; j < 8; ++j) {
        const int rel = j + s;
        r[j] = (rel < 0) ? vm[8 + rel] : ((rel < 8) ? vc[rel] : vp[rel - 8]);
      }
      *(f16x8*)(dst + (size_t)djx * (64 * 4352) + hr * 64 + w8 * 8) = r;
    }
  }
}

// ---------------- Kernel 2: attn via MFMA, wave-disjoint output slices -----
// grid 1600 = XCD-swizzled (b, sh, sp∈0..3); block 256 (4 waves).
// Each wave owns 16 co-rows x 64 ci over the block's K=1024 slice: NO LDS,
// NO cross-wave merge (the old 16K LDS-atomics/block were the ~140µs floor).
// 1-deep register double-buffer prefetch; sp-parts merge via global atomicAdd
// into the memset-zeroed attn_p. Same-b blocks pinned to one XCD (L2-hot).
__global__ __launch_bounds__(256) void k_attn(const _Float16* __restrict__ qkh,
                                              const _Float16* __restrict__ qpad,
                                              float* __restrict__ attn_p) {
  int blk = blockIdx.x;
  int xcd = blk & 7, j = blk >> 3;  // j 0..199
  int b = xcd + ((j >= 100) ? 8 : 0);
  int t = (j >= 100) ? (j - 100) : j;  // 0..99
  int sh = t >> 2, sp = t & 3;
  int djx = sh % 5, dix = sh / 5;
  int tid = threadIdx.x, w = tid >> 6, lane = tid & 63;
  int n16 = lane & 15, quad = lane >> 4;

  const _Float16* ka = qkh + (size_t)(b * 128 + 64 + w * 16 + n16) * HW2 +
                       sp * 1024 + quad * 8;
  const _Float16* qa = qpad + ((size_t)(b * 5 + djx) * 64 + n16) * 4352 +
                       dix * 64 + sp * 1024 + quad * 8;

  f32x4 acc[4];
#pragma unroll
  for (int nt = 0; nt < 4; ++nt) acc[nt] = (f32x4){0.f, 0.f, 0.f, 0.f};

  f16x8 afA, bfA[4], afB, bfB[4];
  afA = *(const f16x8*)ka;
#pragma unroll
  for (int nt = 0; nt < 4; ++nt)
    bfA[nt] = *(const f16x8*)(qa + (size_t)nt * 69632);  // 16*4352

#pragma unroll
  for (int ks = 0; ks < 32; ks += 2) {
    afB = *(const f16x8*)(ka + (ks + 1) * 32);
#pragma unroll
    for (int nt = 0; nt < 4; ++nt)
      bfB[nt] = *(const f16x8*)(qa + (size_t)nt * 69632 + (ks + 1) * 32);
#pragma unroll
    for (int nt = 0; nt < 4; ++nt)
      acc[nt] = __builtin_amdgcn_mfma_f32_16x16x32_f16(afA, bfA[nt], acc[nt],
                                                       0, 0, 0);
    if (ks + 2 < 32) {
      afA = *(const f16x8*)(ka + (ks + 2) * 32);
#pragma unroll
      for (int nt = 0; nt < 4; ++nt)
        bfA[nt] = *(const f16x8*)(qa + (size_t)nt * 69632 + (ks + 2) * 32);
    }
#pragma unroll
    for (int nt = 0; nt < 4; ++nt)
      acc[nt] = __builtin_amdgcn_mfma_f32_16x16x32_f16(afB, bfB[nt], acc[nt],
                                                       0, 0, 0);
  }

  float* op = attn_p + (size_t)(b * 25 + sh) * 4096;
#pragma unroll
  for (int nt = 0; nt < 4; ++nt)
#pragma unroll
    for (int reg = 0; reg < 4; ++reg) {
      int co = w * 16 + quad * 4 + reg;
      atomicAdd(&op[co * 64 + nt * 16 + n16], acc[nt][reg]);
    }
}

// ---------------- Kernel 3: ak_t = valid-conv(attn, weight) ----------------
__global__ __launch_bounds__(576) void k_akconv(const float* __restrict__ attn_p,
                                                const float* __restrict__ wgt,
                                                float* __restrict__ akt) {
  int blk = blockIdx.x;
  int b = blk >> 6, co = blk & 63;
  __shared__ float sa[64 * 25];
  int tid = threadIdx.x;
  for (int e = tid; e < 1600; e += 576) {
    int didj = e >> 6, ci = e & 63;
    size_t idx = (((size_t)b * 25 + didj) * 64 + co) * 64 + ci;
    sa[ci * 25 + didj] = attn_p[idx];
  }
  __syncthreads();
  int o = tid / 9, rs = tid % 9;
  int ki = rs / 3, kj = rs % 3;
  float acc = 0.f;
  for (int ci = 0; ci < 64; ++ci) {
    const float* wp = wgt + (o * 64 + ci) * 9;
    const float* ap = sa + ci * 25 + ki * 5 + kj;
#pragma unroll
    for (int r = 0; r < 3; ++r)
#pragma unroll
      for (int s = 0; s < 3; ++s) acc += ap[r * 5 + s] * wp[r * 3 + s];
  }
  akt[((size_t)(b * 64 + o) * 64 + co) * 9 + rs] = acc;
}

// ---------------- Kernel 4: per-(b,o) norm + fp16 kern assembly ------------
__global__ __launch_bounds__(576) void k_kern(const float* __restrict__ akt,
                                              const float* __restrict__ wgt,
                                              const float* __restrict__ temp,
                                              _Float16* __restrict__ kh) {
  int blk = blockIdx.x;
  int o = blk & 63;
  int tid = threadIdx.x;
  float v = akt[(size_t)blk * 576 + tid];
  float sq = v * v;
#pragma unroll
  for (int m = 1; m < 64; m <<= 1) sq += __shfl_xor(sq, m, 64);
  __shared__ float wsum[9];
  if ((tid & 63) == 0) wsum[tid >> 6] = sq;
  __syncthreads();
  float tot = 0.f;
#pragma unroll
  for (int i = 0; i < 9; ++i) tot += wsum[i];
  float inv = temp[0] / fmaxf(sqrtf(tot), 1e-12f);
  float kv = wgt[o * 576 + tid] + v * inv;
  int b = blk >> 6;
  int ci = tid / 9, rs = tid % 9;
  kh[(((size_t)(b * 9 + rs) * 64 + o) * 64) + ci] = (_Float16)kv;
}

// ---------------- Kernel 5: dynamic 3x3 conv + ReLU, LDS-staged x tile -----
__global__ __launch_bounds__(256, 3) void k_final(const _Float16* __restrict__ xh,
                                                  const _Float16* __restrict__ kh,
                                                  float* __restrict__ out) {
  int blk = blockIdx.x;
  int xt = blk % 3;
  int t2 = blk / 3;
  int yt = t2 % 48, b = t2 / 48;
  int y0 = yt * 4, x0 = xt * 64;

  __shared__ __align__(16) _Float16 xs[6 * 68 * 64];  // 52,224 B -> 3 blocks/CU

  int tid = threadIdx.x;
  int w = tid >> 6, lane = tid & 63;
  int n16 = lane & 15, quad = lane >> 4;

  const _Float16* xb = xh + (size_t)b * (XPH * XPW * 64);
  const _Float16* kb = kh + (size_t)b * (9 * 64 * 64);

  {
    f16x8 v[13];
#pragma unroll
    for (int i = 0; i < 13; ++i) {
      int e = tid + 256 * i;
      if (e < 3264) {
        int row = e / 544, rem = e % 544;
        int px = rem >> 3, c = rem & 7;
        v[i] = *(const f16x8*)(xb + ((size_t)(y0 + row) * XPW + x0 + px) * 64 +
                               c * 8);
      }
    }
#pragma unroll
    for (int i = 0; i < 13; ++i) {
      int e = tid + 256 * i;
      if (e < 3264) {
        int row = e / 544, rem = e % 544;
        int px = rem >> 3, c = rem & 7;
        *(f16x8*)&xs[((row * 68 + px) * 8 + (c ^ (px & 7))) * 8] = v[i];
      }
    }
  }
  __syncthreads();

  f32x4 acc[4][4];
#pragma unroll
  for (int mt = 0; mt < 4; ++mt)
#pragma unroll
    for (int nt = 0; nt < 4; ++nt) acc[mt][nt] = (f32x4){0.f, 0.f, 0.f, 0.f};

#define LDAF(dst, ch_)                                                          \
  {                                                                             \
    const int rs_ = (ch_) >> 1, hi_ = (ch_)&1;                                  \
    _Pragma("unroll") for (int mt = 0; mt < 4; ++mt) dst[mt] =                  \
        *(const f16x8*)(kb + ((size_t)rs_ * 64 + mt * 16 + n16) * 64 +          \
                        hi_ * 32 + quad * 8);                                   \
  }

  f16x8 af[3][4];
  LDAF(af[0], 0)
  LDAF(af[1], 1)

#pragma unroll
  for (int ch = 0; ch < 18; ++ch) {
    if (ch + 2 < 18) LDAF(af[(ch + 2) % 3], ch + 2)
    int rs = ch >> 1, hi = ch & 1;
    int r = rs / 3, s = rs % 3;
    int trow = w + r;  // tile row 0..5
    f16x8 bf[4];
#pragma unroll
    for (int nt = 0; nt < 4; ++nt) {
      int px = nt * 16 + n16 + s;  // 0..65
      int c = (hi * 4 + quad) ^ (px & 7);
      bf[nt] = *(const f16x8*)&xs[((trow * 68 + px) * 8 + c) * 8];
    }
#pragma unroll
    for (int mt = 0; mt < 4; ++mt)
#pragma unroll
      for (int nt = 0; nt < 4; ++nt)
        acc[mt][nt] = __builtin_amdgcn_mfma_f32_16x16x32_f16(af[ch % 3][mt],
                                                             bf[nt], acc[mt][nt],
                                                             0, 0, 0);
  }
#undef LDAF

  int y = y0 + w;
#pragma unroll
  for (int mt = 0; mt < 4; ++mt)
#pragma unroll
    for (int reg = 0; reg < 4; ++reg) {
      int o = mt * 16 + quad * 4 + reg;
      float* op = out + (((size_t)(b * 64 + o) * HH + y) * WW + x0);
#pragma unroll
      for (int nt = 0; nt < 4; ++nt)
        op[nt * 16 + n16] = fmaxf(acc[mt][nt][reg], 0.f);
    }
}

extern "C" void kernel_launch(void* const* d_in, const int* in_sizes, int n_in,
                              void* d_out, int out_size, void* d_ws, size_t ws_size,
                              hipStream_t stream) {
  const float* x = (const float*)d_in[0];     // (16,64,192,192)
  const float* wqk = (const float*)d_in[1];   // (128,64,3,3)
  const float* wgt = (const float*)d_in[2];   // (64,64,3,3)
  const float* temp = (const float*)d_in[3];  // (1,1,1)
  float* out = (float*)d_out;
  char* ws = (char*)d_ws;

  // Workspace layout (bytes):
  _Float16* xh = (_Float16*)ws;                        // 77,873,152 (16*194*196*64*2)
  _Float16* qkh = (_Float16*)(ws + 77873152);          // 16,777,216
  _Float16* qpad = (_Float16*)(ws + 94650368);         // 44,564,480
  float* attn_p = (float*)(ws + 139214848);            //  6,553,600 (atomic-merged)
  // wh aliases the qpad tail: dead before k_qpad writes qpad.
  _Float16* wh = (_Float16*)(ws + 139067392);          //    147,456
  // akt/kh alias the qpad head (qpad dead after k_attn):
  float* akt = (float*)(ws + 94650368);                //  2,359,296
  _Float16* kh = (_Float16*)(ws + 97009664);           //  1,179,648
  // total 145,768,448 B (~145.8 MB)

  hipMemsetAsync(attn_p, 0, 6553600, stream);
  k_wpack<<<dim3(72), 1024, 0, stream>>>(wqk, wh);
  k_xhalo<<<dim3(580), 256, 0, stream>>>(xh);
  k_xpack<<<dim3(9216), 256, 0, stream>>>(x, xh);
  k_qkconv<<<dim3(512), 256, 0, stream>>>(xh, wh, qkh);
  k_qpad<<<dim3(1024), 256, 0, stream>>>(qkh, qpad);
  k_attn<<<dim3(1600), 256, 0, stream>>>(qkh, qpad, attn_p);
  k_akconv<<<dim3(1024), 576, 0, stream>>>(attn_p, wgt, akt);
  k_kern<<<dim3(1024), 576, 0, stream>>>(akt, wgt, temp, kh);
  k_final<<<dim3(2304), 256, 0, stream>>>(xh, kh, out);
}